// Round 1
// baseline (327.690 us; speedup 1.0000x reference)
//
#include <hip/hip_runtime.h>
#include <math.h>

// Problem constants (fixed by setup_inputs): N src points, M targets, D=3.
constexpr int N_SRC = 16384;
constexpr int M_TAR = 16384;
constexpr int QUARTER = N_SRC / 4; // each wave scans one quarter of sources

// --- prep: w[j] = (-2*sx, -2*sy, -2*sz, ||s||^2), and zero the scalar output.
// argmin_j (||t||^2 - 2 t.s + ||s||^2)  ==  argmin_j (w.x*tx + w.y*ty + w.z*tz + w.w)
__global__ void prep_kernel(const float* __restrict__ src,
                            float4* __restrict__ w,
                            float* __restrict__ out) {
    int j = blockIdx.x * blockDim.x + threadIdx.x;
    if (j == 0) out[0] = 0.0f;  // d_out is poisoned 0xAA before every launch
    if (j < N_SRC) {
        float sx = src[3 * j + 0];
        float sy = src[3 * j + 1];
        float sz = src[3 * j + 2];
        w[j] = make_float4(-2.0f * sx, -2.0f * sy, -2.0f * sz,
                           sx * sx + sy * sy + sz * sz);
    }
}

// --- main: block = 256 threads = 4 waves. Wave q (wave-uniform) scans source
// quarter q for 64 consecutive targets (one per lane). w[j] loads are
// wave-uniform -> scalar s_load_dwordx4; vector pipe does 3 FMA + cmp + 2 sel
// per pair. LDS reduce across the 4 waves, then wave-shuffle loss reduction.
__global__ __launch_bounds__(256) void nn_main(const float* __restrict__ src,
                                               const float* __restrict__ tar,
                                               const float4* __restrict__ w,
                                               float* __restrict__ out) {
    const int tid  = threadIdx.x;
    const int lane = tid & 63;
    const int q    = __builtin_amdgcn_readfirstlane(tid >> 6);  // 0..3, uniform
    const int t    = blockIdx.x * 64 + lane;

    const float tx = tar[3 * t + 0];
    const float ty = tar[3 * t + 1];
    const float tz = tar[3 * t + 2];

    const int j0 = q * QUARTER;
    const int j1 = j0 + QUARTER;

    float best = INFINITY;
    int   bi   = j0;
#pragma unroll 8
    for (int j = j0; j < j1; ++j) {
        float4 s = w[j];  // wave-uniform address -> s_load_dwordx4
        float v = fmaf(s.x, tx, fmaf(s.y, ty, fmaf(s.z, tz, s.w)));
        if (v < best) { best = v; bi = j; }  // strict < keeps first (lowest j)
    }

    __shared__ float sv[4][64];
    __shared__ int   si[4][64];
    sv[q][lane] = best;
    si[q][lane] = bi;
    __syncthreads();

    if (tid < 64) {
        float bv = sv[0][lane];
        int   b  = si[0][lane];
        // ascending q => ascending index ranges; strict < keeps lowest index on ties
#pragma unroll
        for (int k = 1; k < 4; ++k) {
            float v = sv[k][lane];
            int   i = si[k][lane];
            if (v < bv) { bv = v; b = i; }
        }
        // loss term from the actual diff (matches reference: 0.5*||src[ii]-tar||^2)
        float dx = src[3 * b + 0] - tx;
        float dy = src[3 * b + 1] - ty;
        float dz = src[3 * b + 2] - tz;
        float term = 0.5f * fmaf(dx, dx, fmaf(dy, dy, dz * dz));
        // wave-64 shuffle reduction
#pragma unroll
        for (int off = 32; off > 0; off >>= 1)
            term += __shfl_down(term, off, 64);
        if (lane == 0) atomicAdd(out, term);
    }
}

// --- fallback if d_ws is too small for the 256 KB w array: compute distances
// directly from src (3 sub + 3 fma per pair instead of 3 fma).
__global__ void zero_out_kernel(float* __restrict__ out) {
    if (threadIdx.x == 0 && blockIdx.x == 0) out[0] = 0.0f;
}

__global__ __launch_bounds__(256) void nn_direct(const float* __restrict__ src,
                                                 const float* __restrict__ tar,
                                                 float* __restrict__ out) {
    const int tid  = threadIdx.x;
    const int lane = tid & 63;
    const int q    = __builtin_amdgcn_readfirstlane(tid >> 6);
    const int t    = blockIdx.x * 64 + lane;

    const float tx = tar[3 * t + 0];
    const float ty = tar[3 * t + 1];
    const float tz = tar[3 * t + 2];

    const int j0 = q * QUARTER;
    const int j1 = j0 + QUARTER;

    float best = INFINITY;
    int   bi   = j0;
#pragma unroll 4
    for (int j = j0; j < j1; ++j) {
        float sx = src[3 * j + 0];  // wave-uniform -> scalar loads
        float sy = src[3 * j + 1];
        float sz = src[3 * j + 2];
        float dx = sx - tx, dy = sy - ty, dz = sz - tz;
        float v = fmaf(dx, dx, fmaf(dy, dy, dz * dz));
        if (v < best) { best = v; bi = j; }
    }

    __shared__ float sv[4][64];
    __shared__ int   si[4][64];
    sv[q][lane] = best;
    si[q][lane] = bi;
    __syncthreads();

    if (tid < 64) {
        float bv = sv[0][lane];
        int   b  = si[0][lane];
#pragma unroll
        for (int k = 1; k < 4; ++k) {
            float v = sv[k][lane];
            int   i = si[k][lane];
            if (v < bv) { bv = v; b = i; }
        }
        float dx = src[3 * b + 0] - tx;
        float dy = src[3 * b + 1] - ty;
        float dz = src[3 * b + 2] - tz;
        float term = 0.5f * fmaf(dx, dx, fmaf(dy, dy, dz * dz));
#pragma unroll
        for (int off = 32; off > 0; off >>= 1)
            term += __shfl_down(term, off, 64);
        if (lane == 0) atomicAdd(out, term);
    }
}

extern "C" void kernel_launch(void* const* d_in, const int* in_sizes, int n_in,
                              void* d_out, int out_size, void* d_ws, size_t ws_size,
                              hipStream_t stream) {
    const float* src = (const float*)d_in[0];  // src_V [N,3] fp32
    const float* tar = (const float*)d_in[1];  // tar_V [M,3] fp32
    float* out = (float*)d_out;                // scalar loss fp32

    if (ws_size >= (size_t)N_SRC * sizeof(float4)) {
        float4* w = (float4*)d_ws;
        prep_kernel<<<N_SRC / 256, 256, 0, stream>>>(src, w, out);
        nn_main<<<M_TAR / 64, 256, 0, stream>>>(src, tar, w, out);
    } else {
        zero_out_kernel<<<1, 64, 0, stream>>>(out);
        nn_direct<<<M_TAR / 64, 256, 0, stream>>>(src, tar, out);
    }
}

// Round 2
// 115.649 us; speedup vs baseline: 2.8335x; 2.8335x over previous
//
#include <hip/hip_runtime.h>
#include <math.h>

// Problem constants (fixed by setup_inputs): N src points, M targets, D=3.
constexpr int N_SRC = 16384;
constexpr int M_TAR = 16384;

// R2 structure: grid (M/64, S_CHUNKS). Block = 4 waves; each wave scans
// PER_WAVE sources for 64 targets (one per lane) with CHAINS independent
// ILP chains. Cross-chunk merge via packed u64 atomicMin.
constexpr int S_CHUNKS = 8;                  // -> 2048 blocks = 8/CU = full occupancy
constexpr int WAVES_PER_BLOCK = 4;
constexpr int PER_WAVE = N_SRC / (S_CHUNKS * WAVES_PER_BLOCK);  // 512
constexpr int CHAINS = 4;                    // independent loads in flight per wave
constexpr int PER_CHAIN = PER_WAVE / CHAINS; // 128

// ws layout: [0,128KB) bests u64[16384]; [128KB,384KB) w float4[16384]
constexpr size_t BESTS_BYTES = (size_t)M_TAR * 8;
constexpr size_t W_BYTES = (size_t)N_SRC * 16;

// w[j] = (-2sx,-2sy,-2sz,||s||^2): argmin_j d2 == argmin_j (w.x*tx+w.y*ty+w.z*tz+w.w)
__global__ void prep2(const float* __restrict__ src, float4* __restrict__ w,
                      unsigned long long* __restrict__ bests, float* __restrict__ out) {
    int j = blockIdx.x * blockDim.x + threadIdx.x;
    if (j == 0) out[0] = 0.0f;  // d_out poisoned 0xAA before every launch
    if (j < N_SRC) {
        float sx = src[3 * j + 0], sy = src[3 * j + 1], sz = src[3 * j + 2];
        w[j] = make_float4(-2.0f * sx, -2.0f * sy, -2.0f * sz,
                           sx * sx + sy * sy + sz * sz);
        bests[j] = ~0ull;  // M_TAR == N_SRC, so this inits all targets' bests
    }
}

__global__ __launch_bounds__(256) void nn_chunks(const float* __restrict__ tar,
                                                 const float4* __restrict__ w,
                                                 unsigned long long* __restrict__ bests) {
    const int tid  = threadIdx.x;
    const int lane = tid & 63;
    const int q    = __builtin_amdgcn_readfirstlane(tid >> 6);  // wave id, uniform
    const int t    = blockIdx.x * 64 + lane;

    const float tx = tar[3 * t + 0];
    const float ty = tar[3 * t + 1];
    const float tz = tar[3 * t + 2];

    // This wave's source range (wave-uniform -> scalar loads of w)
    const int j0 = (blockIdx.y * WAVES_PER_BLOCK + q) * PER_WAVE;
    const float4* base = w + j0;

    float bv[CHAINS];
    int   bi[CHAINS];
#pragma unroll
    for (int c = 0; c < CHAINS; ++c) { bv[c] = INFINITY; bi[c] = 0; }

    for (int i = 0; i < PER_CHAIN; ++i) {
#pragma unroll
        for (int c = 0; c < CHAINS; ++c) {  // 4 independent loads in flight
            float4 s = base[c * PER_CHAIN + i];
            float v = fmaf(s.x, tx, fmaf(s.y, ty, fmaf(s.z, tz, s.w)));
            if (v < bv[c]) { bv[c] = v; bi[c] = i; }  // strict < keeps lowest i
        }
    }
    // merge chains (ascending index ranges; strict < keeps lowest index on ties)
    float best = bv[0];
    int   bidx = j0 + bi[0];
#pragma unroll
    for (int c = 1; c < CHAINS; ++c) {
        int idx = j0 + c * PER_CHAIN + bi[c];
        if (bv[c] < best) { best = bv[c]; bidx = idx; }
    }

    __shared__ float sv[WAVES_PER_BLOCK][64];
    __shared__ int   si[WAVES_PER_BLOCK][64];
    sv[q][lane] = best;
    si[q][lane] = bidx;
    __syncthreads();

    if (tid < 64) {
        float v0 = sv[0][lane];
        int   i0 = si[0][lane];
#pragma unroll
        for (int k = 1; k < WAVES_PER_BLOCK; ++k) {  // ascending wave = ascending idx
            float v = sv[k][lane];
            int   i = si[k][lane];
            if (v < v0) { v0 = v; i0 = i; }
        }
        // monotone float->uint map (handles negative v = d2 - ||t||^2)
        unsigned u = __float_as_uint(v0);
        u = (u & 0x80000000u) ? ~u : (u | 0x80000000u);
        unsigned long long packed = ((unsigned long long)u << 32) | (unsigned)i0;
        atomicMin(&bests[t], packed);  // ties -> lowest index, argmin semantics
    }
}

__global__ __launch_bounds__(256) void finalize2(const float* __restrict__ src,
                                                 const float* __restrict__ tar,
                                                 const unsigned long long* __restrict__ bests,
                                                 float* __restrict__ out) {
    const int t    = blockIdx.x * 256 + threadIdx.x;
    const int lane = threadIdx.x & 63;
    const int wid  = threadIdx.x >> 6;

    int b = (int)(bests[t] & 0xFFFFFFFFull);
    float dx = src[3 * b + 0] - tar[3 * t + 0];
    float dy = src[3 * b + 1] - tar[3 * t + 1];
    float dz = src[3 * b + 2] - tar[3 * t + 2];
    float term = 0.5f * fmaf(dx, dx, fmaf(dy, dy, dz * dz));
#pragma unroll
    for (int off = 32; off > 0; off >>= 1)
        term += __shfl_down(term, off, 64);

    __shared__ float partial[4];
    if (lane == 0) partial[wid] = term;
    __syncthreads();
    if (threadIdx.x == 0)
        atomicAdd(out, partial[0] + partial[1] + partial[2] + partial[3]);
}

// ---------------- fallback paths (small ws) — unchanged from R1 ----------------
constexpr int QUARTER = N_SRC / 4;

__global__ void prep_kernel(const float* __restrict__ src, float4* __restrict__ w,
                            float* __restrict__ out) {
    int j = blockIdx.x * blockDim.x + threadIdx.x;
    if (j == 0) out[0] = 0.0f;
    if (j < N_SRC) {
        float sx = src[3 * j + 0], sy = src[3 * j + 1], sz = src[3 * j + 2];
        w[j] = make_float4(-2.0f * sx, -2.0f * sy, -2.0f * sz,
                           sx * sx + sy * sy + sz * sz);
    }
}

__global__ __launch_bounds__(256) void nn_main(const float* __restrict__ src,
                                               const float* __restrict__ tar,
                                               const float4* __restrict__ w,
                                               float* __restrict__ out) {
    const int tid  = threadIdx.x;
    const int lane = tid & 63;
    const int q    = __builtin_amdgcn_readfirstlane(tid >> 6);
    const int t    = blockIdx.x * 64 + lane;
    const float tx = tar[3 * t + 0], ty = tar[3 * t + 1], tz = tar[3 * t + 2];
    const int j0 = q * QUARTER, j1 = j0 + QUARTER;
    float best = INFINITY;
    int   bi   = j0;
#pragma unroll 8
    for (int j = j0; j < j1; ++j) {
        float4 s = w[j];
        float v = fmaf(s.x, tx, fmaf(s.y, ty, fmaf(s.z, tz, s.w)));
        if (v < best) { best = v; bi = j; }
    }
    __shared__ float sv[4][64];
    __shared__ int   si[4][64];
    sv[q][lane] = best; si[q][lane] = bi;
    __syncthreads();
    if (tid < 64) {
        float bv = sv[0][lane]; int b = si[0][lane];
#pragma unroll
        for (int k = 1; k < 4; ++k) {
            float v = sv[k][lane]; int i = si[k][lane];
            if (v < bv) { bv = v; b = i; }
        }
        float dx = src[3 * b + 0] - tx, dy = src[3 * b + 1] - ty, dz = src[3 * b + 2] - tz;
        float term = 0.5f * fmaf(dx, dx, fmaf(dy, dy, dz * dz));
#pragma unroll
        for (int off = 32; off > 0; off >>= 1) term += __shfl_down(term, off, 64);
        if (lane == 0) atomicAdd(out, term);
    }
}

__global__ void zero_out_kernel(float* __restrict__ out) {
    if (threadIdx.x == 0 && blockIdx.x == 0) out[0] = 0.0f;
}

__global__ __launch_bounds__(256) void nn_direct(const float* __restrict__ src,
                                                 const float* __restrict__ tar,
                                                 float* __restrict__ out) {
    const int tid  = threadIdx.x;
    const int lane = tid & 63;
    const int q    = __builtin_amdgcn_readfirstlane(tid >> 6);
    const int t    = blockIdx.x * 64 + lane;
    const float tx = tar[3 * t + 0], ty = tar[3 * t + 1], tz = tar[3 * t + 2];
    const int j0 = q * QUARTER, j1 = j0 + QUARTER;
    float best = INFINITY;
    int   bi   = j0;
#pragma unroll 4
    for (int j = j0; j < j1; ++j) {
        float sx = src[3 * j + 0], sy = src[3 * j + 1], sz = src[3 * j + 2];
        float dx = sx - tx, dy = sy - ty, dz = sz - tz;
        float v = fmaf(dx, dx, fmaf(dy, dy, dz * dz));
        if (v < best) { best = v; bi = j; }
    }
    __shared__ float sv[4][64];
    __shared__ int   si[4][64];
    sv[q][lane] = best; si[q][lane] = bi;
    __syncthreads();
    if (tid < 64) {
        float bv = sv[0][lane]; int b = si[0][lane];
#pragma unroll
        for (int k = 1; k < 4; ++k) {
            float v = sv[k][lane]; int i = si[k][lane];
            if (v < bv) { bv = v; b = i; }
        }
        float dx = src[3 * b + 0] - tx, dy = src[3 * b + 1] - ty, dz = src[3 * b + 2] - tz;
        float term = 0.5f * fmaf(dx, dx, fmaf(dy, dy, dz * dz));
#pragma unroll
        for (int off = 32; off > 0; off >>= 1) term += __shfl_down(term, off, 64);
        if (lane == 0) atomicAdd(out, term);
    }
}

extern "C" void kernel_launch(void* const* d_in, const int* in_sizes, int n_in,
                              void* d_out, int out_size, void* d_ws, size_t ws_size,
                              hipStream_t stream) {
    const float* src = (const float*)d_in[0];  // src_V [N,3] fp32
    const float* tar = (const float*)d_in[1];  // tar_V [M,3] fp32
    float* out = (float*)d_out;                // scalar loss fp32

    if (ws_size >= BESTS_BYTES + W_BYTES) {
        unsigned long long* bests = (unsigned long long*)d_ws;
        float4* w = (float4*)((char*)d_ws + BESTS_BYTES);
        prep2<<<N_SRC / 256, 256, 0, stream>>>(src, w, bests, out);
        nn_chunks<<<dim3(M_TAR / 64, S_CHUNKS), 256, 0, stream>>>(tar, w, bests);
        finalize2<<<M_TAR / 256, 256, 0, stream>>>(src, tar, bests, out);
    } else if (ws_size >= W_BYTES) {
        float4* w = (float4*)d_ws;
        prep_kernel<<<N_SRC / 256, 256, 0, stream>>>(src, w, out);
        nn_main<<<M_TAR / 64, 256, 0, stream>>>(src, tar, w, out);
    } else {
        zero_out_kernel<<<1, 64, 0, stream>>>(out);
        nn_direct<<<M_TAR / 64, 256, 0, stream>>>(src, tar, out);
    }
}